// Round 11
// baseline (278.050 us; speedup 1.0000x reference)
//
#include <hip/hip_runtime.h>

#define NB 128
#define NP 8732
#define NO 32
#define NC 21
#define NCHUNK 35   // k_loss-role blocks per image (256 priors each)
#define NOBLK 16    // k_obj-role blocks per image (2 objects each)

// ---------------- workspace layout (no zero-init required anywhere) ----------
// pfor    : int[NB*NO]      @ 0        per-(b,o) argmax prior (plain store)
// pd0     : double[NB*35]   @ 16384    per-chunk pos_conf partial (UNFORCED)
// pd1     : double[NB*35]   @ 52224    per-chunk loc partial (UNFORCED)
// pnp     : int[NB*35]      @ 88064    per-chunk npos partial (UNFORCED)
// snp     : int[NB]         @ 105984   per-image npos (k_tail, corrected)
// sums    : double[NB*3]    @ 106496   per-image {hn, pos_conf, loc} (corrected)
// donecnt : int             @ 109568   zeroed by k_main block (0,0)
// confneg : float[NB*NP]    @ 109824   (patched by k_tail fixup)
// code    : int[NB*NP]      @ 4580608  obj | mat<<8 (unforced match state)

// -------- wave64 reductions via DPP (VALU pipe); result uniform via readlane(63)
__device__ __forceinline__ float wave64_fmax_u(float m) {
    int v;
    v = __builtin_amdgcn_update_dpp(__float_as_int(m), __float_as_int(m), 0x111, 0xf, 0xf, false);
    m = fmaxf(m, __int_as_float(v));
    v = __builtin_amdgcn_update_dpp(__float_as_int(m), __float_as_int(m), 0x112, 0xf, 0xf, false);
    m = fmaxf(m, __int_as_float(v));
    v = __builtin_amdgcn_update_dpp(__float_as_int(m), __float_as_int(m), 0x114, 0xf, 0xf, false);
    m = fmaxf(m, __int_as_float(v));
    v = __builtin_amdgcn_update_dpp(__float_as_int(m), __float_as_int(m), 0x118, 0xf, 0xf, false);
    m = fmaxf(m, __int_as_float(v));
    v = __builtin_amdgcn_update_dpp(__float_as_int(m), __float_as_int(m), 0x142, 0xf, 0xf, false);
    m = fmaxf(m, __int_as_float(v));
    v = __builtin_amdgcn_update_dpp(__float_as_int(m), __float_as_int(m), 0x143, 0xf, 0xf, false);
    m = fmaxf(m, __int_as_float(v));
    return __int_as_float(__builtin_amdgcn_readlane(__float_as_int(m), 63));
}

__device__ __forceinline__ int wave64_imin_u(int m) {
    int v;
    v = __builtin_amdgcn_update_dpp(m, m, 0x111, 0xf, 0xf, false); m = v < m ? v : m;
    v = __builtin_amdgcn_update_dpp(m, m, 0x112, 0xf, 0xf, false); m = v < m ? v : m;
    v = __builtin_amdgcn_update_dpp(m, m, 0x114, 0xf, 0xf, false); m = v < m ? v : m;
    v = __builtin_amdgcn_update_dpp(m, m, 0x118, 0xf, 0xf, false); m = v < m ? v : m;
    v = __builtin_amdgcn_update_dpp(m, m, 0x142, 0xf, 0xf, false); m = v < m ? v : m;
    v = __builtin_amdgcn_update_dpp(m, m, 0x143, 0xf, 0xf, false); m = v < m ? v : m;
    return __builtin_amdgcn_readlane(m, 63);
}

// Fused launch 1 under __launch_bounds__(256,8) (VGPR<=64 so BOTH roles keep
// 8 waves/SIMD): blockIdx.x < NCHUNK -> k_loss role (256 priors, unforced);
// blockIdx.x >= NCHUNK -> k_obj role (2 objects over all priors; 2-object
// blocks keep the live set ~40 VGPR, no spill under the cap).
__global__ __launch_bounds__(256, 8) void k_main(const float* __restrict__ plocs,
                                                 const float* __restrict__ scores,
                                                 const float* __restrict__ boxes,
                                                 const int* __restrict__ labels,
                                                 const float* __restrict__ priors,
                                                 float* __restrict__ confneg,
                                                 int* __restrict__ code,
                                                 int* __restrict__ pnp,
                                                 double* __restrict__ pd0,
                                                 double* __restrict__ pd1,
                                                 int* __restrict__ pfor,
                                                 int* __restrict__ donecnt) {
    int b = blockIdx.y;
    int tid = threadIdx.x, lane = tid & 63, wid = tid >> 6;

    if (blockIdx.x >= NCHUNK) {
        // ---------------- k_obj role (2 objects) ----------------
        __shared__ unsigned long long part[4][2];   // [wave][object]
        int o0 = (blockIdx.x - NCHUNK) * 2;

        float4 bx[2]; float a1[2];
#pragma unroll
        for (int i = 0; i < 2; ++i) {
            bx[i] = ((const float4*)boxes)[b * NO + o0 + i];   // uniform -> s_load
            a1[i] = (bx[i].z - bx[i].x) * (bx[i].w - bx[i].y);
        }
        float bv[2]; int bp[2];
#pragma unroll
        for (int i = 0; i < 2; ++i) { bv[i] = 0.0f; bp[i] = tid; }  // all-zero col -> p=0
        const float4* pr4 = (const float4*)priors;

        for (int k = 0; k < 34; ++k) {               // p <= 255+8448 = 8703 < NP
            int p = tid + (k << 8);
            float4 pr = pr4[p];
            float x1 = pr.x - pr.z * 0.5f, y1 = pr.y - pr.w * 0.5f;
            float x2 = pr.x + pr.z * 0.5f, y2 = pr.y + pr.w * 0.5f;
            float pa = (x2 - x1) * (y2 - y1);
#pragma unroll
            for (int i = 0; i < 2; ++i) {
                float lx = fmaxf(bx[i].x, x1), ly = fmaxf(bx[i].y, y1);
                float hx = fminf(bx[i].z, x2), hy = fminf(bx[i].w, y2);
                float inter = fmaxf(hx - lx, 0.0f) * fmaxf(hy - ly, 0.0f);
                float iou = inter / (a1[i] + pa - inter);  // same expr/order as ref
                if (iou > bv[i]) { bv[i] = iou; bp[i] = p; }  // ascending p: first max
            }
        }
        {   // tail: p = tid + 8704, valid for tid < 28
            int p = tid + 8704;
            if (p < NP) {
                float4 pr = pr4[p];
                float x1 = pr.x - pr.z * 0.5f, y1 = pr.y - pr.w * 0.5f;
                float x2 = pr.x + pr.z * 0.5f, y2 = pr.y + pr.w * 0.5f;
                float pa = (x2 - x1) * (y2 - y1);
#pragma unroll
                for (int i = 0; i < 2; ++i) {
                    float lx = fmaxf(bx[i].x, x1), ly = fmaxf(bx[i].y, y1);
                    float hx = fminf(bx[i].z, x2), hy = fminf(bx[i].w, y2);
                    float inter = fmaxf(hx - lx, 0.0f) * fmaxf(hy - ly, 0.0f);
                    float iou = inter / (a1[i] + pa - inter);
                    if (iou > bv[i]) { bv[i] = iou; bp[i] = p; }
                }
            }
        }
#pragma unroll
        for (int i = 0; i < 2; ++i) {
            float m = wave64_fmax_u(bv[i]);                      // exact wave max
            int mp = wave64_imin_u((bv[i] == m) ? bp[i] : 0x7FFFFFFF);  // min p @ max
            if (lane == 0)
                part[wid][i] = ((unsigned long long)__float_as_uint(m) << 32) |
                               (unsigned long long)(0xFFFFFFFFu - (unsigned)mp);
        }
        __syncthreads();
        if (tid < 2) {   // combine 4 wave-partials for object o0+tid
            unsigned long long best = part[0][tid];
            if (part[1][tid] > best) best = part[1][tid];
            if (part[2][tid] > best) best = part[2][tid];
            if (part[3][tid] > best) best = part[3][tid];
            pfor[b * NO + o0 + tid] = (int)(0xFFFFFFFFu - (unsigned)(best & 0xFFFFFFFFull));
        }
        return;
    }

    // ---------------- k_loss role (unforced; R6 shape, no pfor) ----------------
    __shared__ float4 sbox[NO];
    __shared__ float  sa1[NO];
    __shared__ int    slbl[NO];
    int p0 = blockIdx.x * 256;

    if (tid < NO) {
        float4 bxx = ((const float4*)boxes)[b * NO + tid];
        sbox[tid] = bxx;
        sa1[tid]  = (bxx.z - bxx.x) * (bxx.w - bxx.y);
        slbl[tid] = labels[b * NO + tid];
    }
    __syncthreads();

    int p = p0 + tid;
    float posconf = 0.0f, locpart = 0.0f;
    int isp = 0;

    if (p < NP) {
        float4 pr = ((const float4*)priors)[p];
        float px1 = pr.x - pr.z * 0.5f, py1 = pr.y - pr.w * 0.5f;
        float px2 = pr.x + pr.z * 0.5f, py2 = pr.y + pr.w * 0.5f;
        float pa  = (px2 - px1) * (py2 - py1);

        // per-prior argmax over 32 objects (sbox/sa1 reads are broadcasts);
        // bestv=0 init: all-zero rows -> index 0, matching jnp.argmax
        float bestv = 0.0f; int besto = 0;
#pragma unroll
        for (int o = 0; o < NO; ++o) {
            float4 bxx = sbox[o];
            float lx = fmaxf(bxx.x, px1), ly = fmaxf(bxx.y, py1);
            float hx = fminf(bxx.z, px2), hy = fminf(bxx.w, py2);
            float inter = fmaxf(hx - lx, 0.0f) * fmaxf(hy - ly, 0.0f);
            float iou = inter / (sa1[o] + pa - inter);  // same expr/order as ref
            if (iou > bestv) { bestv = iou; besto = o; }  // first max wins
        }
        int mat = bestv >= 0.5f ? 1 : 0;
        int lbl = mat ? slbl[besto] : 0;
        code[(size_t)b * NP + p] = besto | (mat << 8);   // for k_tail fixup

        // score row loads (after argmax -> VGPR-lean)
        const float* srow = scores + ((size_t)b * NP + p) * NC;
        const float4* r4 = (const float4*)srow;
        float4 q0 = r4[0], q1 = r4[1], q2 = r4[2], q3 = r4[3], q4 = r4[4];
        float sl = srow[lbl];   // one scatter dword; exact same bits as s[lbl]

        float s[NC] = {q0.x, q0.y, q0.z, q0.w, q1.x, q1.y, q1.z, q1.w,
                       q2.x, q2.y, q2.z, q2.w, q3.x, q3.y, q3.z, q3.w,
                       q4.x, q4.y, q4.z, q4.w, srow[20]};
        float m = s[0];
#pragma unroll
        for (int c = 1; c < NC; ++c) m = fmaxf(m, s[c]);
        float sum = 0.0f;
#pragma unroll
        for (int c = 0; c < NC; ++c) sum += __expf(s[c] - m);  // ascending c order
        float conf = m + __logf(sum) - sl;

        if (lbl != 0) {
            isp = 1;
            posconf = conf;
            float4 bxx = sbox[besto];
            float cx = (bxx.x + bxx.z) * 0.5f, cy = (bxx.y + bxx.w) * 0.5f;
            float w = bxx.z - bxx.x, h = bxx.w - bxx.y;
            float gx = (cx - pr.x) / (pr.z * 0.1f);
            float gy = (cy - pr.y) / (pr.w * 0.1f);
            float gw = __logf(w / pr.z) * 5.0f;
            float gh = __logf(h / pr.w) * 5.0f;
            float4 pl = ((const float4*)plocs)[(size_t)b * NP + p];
            locpart = fabsf(pl.x - gx) + fabsf(pl.y - gy) +
                      fabsf(pl.z - gw) + fabsf(pl.w - gh);
        }
        confneg[(size_t)b * NP + p] = isp ? 0.0f : conf;
    }

    // wave shuffle reduce, then 4-wave LDS combine, one barrier
    for (int s = 32; s > 0; s >>= 1) {
        posconf += __shfl_xor(posconf, s, 64);
        locpart += __shfl_xor(locpart, s, 64);
        isp     += __shfl_xor(isp, s, 64);
    }
    __shared__ float w0[4], w1[4];
    __shared__ int wc[4];
    if (lane == 0) { w0[wid] = posconf; w1[wid] = locpart; wc[wid] = isp; }
    __syncthreads();
    if (tid == 0) {
        int pb = b * NCHUNK + blockIdx.x;
        pd0[pb] = (double)(w0[0] + w0[1] + w0[2] + w0[3]);
        pd1[pb] = (double)(w1[0] + w1[1] + w1[2] + w1[3]);
        pnp[pb] = wc[0] + wc[1] + wc[2] + wc[3];
        if (pb == 0) *donecnt = 0;   // stream-ordered before k_tail; poison-proof
    }
}

// Launch 2: fixup (apply forced-prior corrections in f64, patch confneg) +
// exact k-th-largest radix-4 bisection + last-block final reduction.
__global__ __launch_bounds__(1024) void k_tail(const float* __restrict__ plocs,
                                               const float* __restrict__ scores,
                                               const float* __restrict__ boxes,
                                               const int* __restrict__ labels,
                                               const float* __restrict__ priors,
                                               const int* __restrict__ pfor,
                                               const int* __restrict__ code,
                                               float* __restrict__ confneg,
                                               const int* __restrict__ pnp,
                                               const double* __restrict__ pd0,
                                               const double* __restrict__ pd1,
                                               int* __restrict__ snp,
                                               double* __restrict__ sums,  // [NB][3] hn,pc,lc
                                               int* __restrict__ donecnt,
                                               float* __restrict__ out) {
    __shared__ unsigned long long sq[2][16];
    __shared__ int    siw[16];
    __shared__ double sdd[16];
    __shared__ int    sk;
    __shared__ int    sfp[NO];
    int tid = threadIdx.x, b = blockIdx.x;
    int lane = tid & 63, wid = tid >> 6;

    // prologue: wave 0 reduces the 35 unforced partials of image b
    int np_ = 0; double d0 = 0.0, d1 = 0.0;
    if (wid == 0) {
        if (lane < NCHUNK) {
            int pb = b * NCHUNK + lane;
            np_ = pnp[pb]; d0 = pd0[pb]; d1 = pd1[pb];
        }
        for (int s = 32; s > 0; s >>= 1) {
            np_ += __shfl_xor(np_, s, 64);
            d0  += __shfl_xor(d0, s, 64);
            d1  += __shfl_xor(d1, s, 64);
        }
        if (lane < NO) sfp[lane] = pfor[b * NO + lane];
    }
    __syncthreads();   // sfp visible

    // fixup (wave 0): apply forced overrides as f64 corrections.
    if (wid == 0) {
        int dnp = 0; double dpos = 0.0, dloc = 0.0;
        if (lane < NO) {
            int p = sfp[lane];
            bool winner = true;                      // last o wins on duplicate p
            for (int o2 = lane + 1; o2 < NO; ++o2)
                if (sfp[o2] == p) winner = false;
            if (winner) {
                int cd = code[(size_t)b * NP + p];
                int obj_old = cd & 255, mat_old = cd >> 8;
                if (!(mat_old && obj_old == (int)lane)) {   // else state unchanged
                    int lbl_old = mat_old ? labels[b * NO + obj_old] : 0;
                    int lbl_new = labels[b * NO + lane];
                    const float* srow = scores + ((size_t)b * NP + p) * NC;
                    float s[NC];
#pragma unroll
                    for (int c = 0; c < NC; ++c) s[c] = srow[c];
                    float m = s[0];
#pragma unroll
                    for (int c = 1; c < NC; ++c) m = fmaxf(m, s[c]);
                    float sum = 0.0f;
#pragma unroll
                    for (int c = 0; c < NC; ++c) sum += __expf(s[c] - m);
                    // identical expr/order to k_main: (m + log(sum)) - s[lbl]
                    float conf_old = m + __logf(sum) - srow[lbl_old];
                    float conf_new = m + __logf(sum) - srow[lbl_new];
                    int io = lbl_old != 0, in_ = lbl_new != 0;
                    dnp  = in_ - io;
                    dpos = (in_ ? (double)conf_new : 0.0) - (io ? (double)conf_old : 0.0);
                    float4 pr = ((const float4*)priors)[p];
                    float4 pl = ((const float4*)plocs)[(size_t)b * NP + p];
                    float ln = 0.0f, lo = 0.0f;
                    {
                        float4 bxx = ((const float4*)boxes)[b * NO + lane];
                        float cx = (bxx.x + bxx.z) * 0.5f, cy = (bxx.y + bxx.w) * 0.5f;
                        float w = bxx.z - bxx.x, h = bxx.w - bxx.y;
                        float gx = (cx - pr.x) / (pr.z * 0.1f);
                        float gy = (cy - pr.y) / (pr.w * 0.1f);
                        float gw = __logf(w / pr.z) * 5.0f;
                        float gh = __logf(h / pr.w) * 5.0f;
                        ln = fabsf(pl.x - gx) + fabsf(pl.y - gy) +
                             fabsf(pl.z - gw) + fabsf(pl.w - gh);
                    }
                    if (io) {
                        float4 bxx = ((const float4*)boxes)[b * NO + obj_old];
                        float cx = (bxx.x + bxx.z) * 0.5f, cy = (bxx.y + bxx.w) * 0.5f;
                        float w = bxx.z - bxx.x, h = bxx.w - bxx.y;
                        float gx = (cx - pr.x) / (pr.z * 0.1f);
                        float gy = (cy - pr.y) / (pr.w * 0.1f);
                        float gw = __logf(w / pr.z) * 5.0f;
                        float gh = __logf(h / pr.w) * 5.0f;
                        lo = fabsf(pl.x - gx) + fabsf(pl.y - gy) +
                             fabsf(pl.z - gw) + fabsf(pl.w - gh);
                    }
                    dloc = (in_ ? (double)ln : 0.0) - (io ? (double)lo : 0.0);
                    confneg[(size_t)b * NP + p] = in_ ? 0.0f : conf_new;
                }
            }
        }
        for (int s = 32; s > 0; s >>= 1) {
            dnp  += __shfl_xor(dnp, s, 64);
            dpos += __shfl_xor(dpos, s, 64);
            dloc += __shfl_xor(dloc, s, 64);
        }
        np_ += dnp; d0 += dpos; d1 += dloc;
        if (lane == 0) {
            int k = np_ * 3; if (k > NP) k = NP;
            sk = k;
            snp[b] = np_;
            sums[b * 3 + 1] = d0;
            sums[b * 3 + 2] = d1;
        }
    }
    __threadfence_block();   // confneg patches visible to block
    __syncthreads();

    const float* src = confneg + (size_t)b * NP;
    float val[9];
#pragma unroll
    for (int j = 0; j < 9; ++j) {
        int i = tid + j * 1024;
        val[j] = (i < NP) ? src[i] : 0.0f;  // 0 never counts (cand>0)
    }
    int k = sk;

    double hn = 0.0;
    if (k > 0) {   // block-uniform
        unsigned T = 0;
        int par = 0;
        {   // step 1: bit 30 (radix-2)
            unsigned cand = 1u << 30;
            int cnt = 0;
#pragma unroll
            for (int j = 0; j < 9; ++j)
                cnt += __popcll(__ballot(__float_as_uint(val[j]) >= cand));
            if (lane == 0) sq[par][wid] = (unsigned long long)cnt;
            __syncthreads();
            unsigned long long t = 0;
#pragma unroll
            for (int w = 0; w < 16; ++w) t += sq[par][w];
            par ^= 1;
            if ((int)t >= k) T = cand;
        }
        // 15 radix-4 steps over bit pairs (29,28)...(1,0)
        for (int sh = 28; sh >= 0; sh -= 2) {
            unsigned c1 = T | (1u << sh), c2 = T | (2u << sh), c3 = T | (3u << sh);
            int n1 = 0, n2 = 0, n3 = 0;
#pragma unroll
            for (int j = 0; j < 9; ++j) {
                unsigned u = __float_as_uint(val[j]);
                n1 += __popcll(__ballot(u >= c1));
                n2 += __popcll(__ballot(u >= c2));
                n3 += __popcll(__ballot(u >= c3));
            }
            if (lane == 0)
                sq[par][wid] = (unsigned long long)n1 |
                               ((unsigned long long)n2 << 20) |
                               ((unsigned long long)n3 << 40);
            __syncthreads();
            unsigned long long t = 0;
#pragma unroll
            for (int w = 0; w < 16; ++w) t += sq[par][w];
            par ^= 1;
            int t1 = (int)(t & 0xFFFFF), t2 = (int)((t >> 20) & 0xFFFFF),
                t3 = (int)((t >> 40) & 0xFFFFF);
            if      (t3 >= k) T = c3;
            else if (t2 >= k) T = c2;
            else if (t1 >= k) T = c1;   // uniform decision
        }

        int cgt = 0;
        double sgt = 0.0;
#pragma unroll
        for (int j = 0; j < 9; ++j) {
            unsigned u = __float_as_uint(val[j]);
            if (u > T) { cgt++; sgt += (double)val[j]; }
        }
        for (int s = 32; s > 0; s >>= 1) {
            cgt += __shfl_xor(cgt, s, 64);
            sgt += __shfl_xor(sgt, s, 64);
        }
        if (lane == 0) { siw[wid] = cgt; sdd[wid] = sgt; }
        __syncthreads();
        if (tid == 0) {
            int cg = 0; double sg = 0.0;
            for (int w = 0; w < 16; ++w) { cg += siw[w]; sg += sdd[w]; }
            hn = sg + (double)(k - cg) * (double)__uint_as_float(T);
        }
    }
    if (tid == 0) sums[b * 3 + 0] = hn;  // explicit 0 when k<=0 (overwrite poison)

    // ---- last-block final reduction ----
    __shared__ int samlast;
    if (tid == 0) {
        __threadfence();                   // sums/snp stores visible device-wide
        int prev = atomicAdd(donecnt, 1);  // device-scope
        samlast = (prev == NB - 1) ? 1 : 0;
    }
    __syncthreads();
    if (!samlast) return;
    __threadfence();

    double hnn = 0.0, pc = 0.0, lc = 0.0, npd = 0.0;
    if (tid < NB) {   // peer-written: atomic reads to dodge stale caches
        hnn = atomicAdd(&sums[tid * 3 + 0], 0.0);
        pc  = atomicAdd(&sums[tid * 3 + 1], 0.0);
        lc  = atomicAdd(&sums[tid * 3 + 2], 0.0);
        npd = (double)atomicAdd((int*)&snp[tid], 0);
    }
    for (int s = 32; s > 0; s >>= 1) {
        hnn += __shfl_xor(hnn, s, 64);
        pc  += __shfl_xor(pc, s, 64);
        lc  += __shfl_xor(lc, s, 64);
        npd += __shfl_xor(npd, s, 64);
    }
    __shared__ double sfin[4][2];
    if (lane == 0 && wid < 2) {
        sfin[0][wid] = hnn; sfin[1][wid] = pc; sfin[2][wid] = lc; sfin[3][wid] = npd;
    }
    __syncthreads();
    if (tid == 0) {
        double H  = sfin[0][0] + sfin[0][1];
        double P  = sfin[1][0] + sfin[1][1];
        double L  = sfin[2][0] + sfin[2][1];
        double nt = sfin[3][0] + sfin[3][1];
        out[0] = (float)((H + P) / nt + L / (nt * 4.0));
    }
}

extern "C" void kernel_launch(void* const* d_in, const int* in_sizes, int n_in,
                              void* d_out, int out_size, void* d_ws, size_t ws_size,
                              hipStream_t stream) {
    const float* plocs  = (const float*)d_in[0];
    const float* scores = (const float*)d_in[1];
    const float* boxes  = (const float*)d_in[2];
    const int*   labels = (const int*)d_in[3];
    const float* priors = (const float*)d_in[4];
    float* out = (float*)d_out;

    char* ws = (char*)d_ws;
    int*    pfor    = (int*)ws;
    double* pd0     = (double*)(ws + 16384);
    double* pd1     = (double*)(ws + 52224);
    int*    pnp     = (int*)(ws + 88064);
    int*    snp     = (int*)(ws + 105984);
    double* sums    = (double*)(ws + 106496);
    int*    donecnt = (int*)(ws + 109568);
    float*  confneg = (float*)(ws + 109824);
    int*    code    = (int*)(ws + 4580608);

    hipLaunchKernelGGL(k_main, dim3(NCHUNK + NOBLK, NB), dim3(256), 0, stream,
                       plocs, scores, boxes, labels, priors,
                       confneg, code, pnp, pd0, pd1, pfor, donecnt);
    hipLaunchKernelGGL(k_tail, dim3(NB), dim3(1024), 0, stream,
                       plocs, scores, boxes, labels, priors, pfor, code,
                       confneg, pnp, pd0, pd1, snp, sums, donecnt, out);
}

// Round 12
// 221.129 us; speedup vs baseline: 1.2574x; 1.2574x over previous
//
#include <hip/hip_runtime.h>

#define NB 128
#define NP 8732
#define NO 32
#define NC 21
#define NCHUNK 35   // k_loss grid.x (256 priors per block)

// ---------------- workspace layout (no zero-init required anywhere) ----------
// pfor   : int[NB*NO]        @ 0        per-(b,o) argmax prior (plain store)
// pd0    : double[NB*35]     @ 16384    per-loss-block pos_conf partial
// pd1    : double[NB*35]     @ 52224    per-loss-block loc partial
// pnp    : int[NB*35]        @ 88064    per-loss-block npos partial
// snp    : int[NB]           @ 105984   per-image npos (k_topk)
// sums   : double[NB*3]      @ 106496   per-image {hn, pos_conf, loc} (k_topk)
// donecnt: int               @ 109568   zeroed by k_loss block pb==0
// confneg: float[NB*NP]      @ 109824

// -------- wave64 reductions via DPP (VALU pipe); result uniform via readlane(63)
__device__ __forceinline__ float wave64_fmax_u(float m) {
    int v;
    v = __builtin_amdgcn_update_dpp(__float_as_int(m), __float_as_int(m), 0x111, 0xf, 0xf, false);
    m = fmaxf(m, __int_as_float(v));
    v = __builtin_amdgcn_update_dpp(__float_as_int(m), __float_as_int(m), 0x112, 0xf, 0xf, false);
    m = fmaxf(m, __int_as_float(v));
    v = __builtin_amdgcn_update_dpp(__float_as_int(m), __float_as_int(m), 0x114, 0xf, 0xf, false);
    m = fmaxf(m, __int_as_float(v));
    v = __builtin_amdgcn_update_dpp(__float_as_int(m), __float_as_int(m), 0x118, 0xf, 0xf, false);
    m = fmaxf(m, __int_as_float(v));
    v = __builtin_amdgcn_update_dpp(__float_as_int(m), __float_as_int(m), 0x142, 0xf, 0xf, false);
    m = fmaxf(m, __int_as_float(v));
    v = __builtin_amdgcn_update_dpp(__float_as_int(m), __float_as_int(m), 0x143, 0xf, 0xf, false);
    m = fmaxf(m, __int_as_float(v));
    return __int_as_float(__builtin_amdgcn_readlane(__float_as_int(m), 63));
}

__device__ __forceinline__ int wave64_imin_u(int m) {
    int v;
    v = __builtin_amdgcn_update_dpp(m, m, 0x111, 0xf, 0xf, false); m = v < m ? v : m;
    v = __builtin_amdgcn_update_dpp(m, m, 0x112, 0xf, 0xf, false); m = v < m ? v : m;
    v = __builtin_amdgcn_update_dpp(m, m, 0x114, 0xf, 0xf, false); m = v < m ? v : m;
    v = __builtin_amdgcn_update_dpp(m, m, 0x118, 0xf, 0xf, false); m = v < m ? v : m;
    v = __builtin_amdgcn_update_dpp(m, m, 0x142, 0xf, 0xf, false); m = v < m ? v : m;
    v = __builtin_amdgcn_update_dpp(m, m, 0x143, 0xf, 0xf, false); m = v < m ? v : m;
    return __builtin_amdgcn_readlane(m, 63);
}

// Per-(b,o) argmax over all priors (R7 version, verified in the 220.36 run).
// grid (8,NB): block owns 4 objects (boxes uniform -> SGPRs); thread scans
// p = tid + 256k (coalesced float4, one load feeds 4 independent argmaxes).
// Per-wave DPP reduce per object, packed u64 partials in LDS, 4-entry combine.
__global__ __launch_bounds__(256) void k_obj(const float* __restrict__ boxes,
                                             const float* __restrict__ priors,
                                             int* __restrict__ pfor) {
    __shared__ unsigned long long part[4][4];   // [wave][object]
    int b = blockIdx.y;
    int tid = threadIdx.x, lane = tid & 63, wid = tid >> 6;
    int o0 = blockIdx.x * 4;

    float4 bx[4]; float a1[4];
#pragma unroll
    for (int i = 0; i < 4; ++i) {
        bx[i] = ((const float4*)boxes)[b * NO + o0 + i];   // uniform -> s_load
        a1[i] = (bx[i].z - bx[i].x) * (bx[i].w - bx[i].y);
    }

    float bv[4] = {-1.0f, -1.0f, -1.0f, -1.0f};
    int   bp[4] = {0, 0, 0, 0};
    const float4* pr4 = (const float4*)priors;

    for (int k = 0; k < 34; ++k) {               // p <= 255+8448 = 8703 < NP
        int p = tid + (k << 8);
        float4 pr = pr4[p];
        float x1 = pr.x - pr.z * 0.5f, y1 = pr.y - pr.w * 0.5f;
        float x2 = pr.x + pr.z * 0.5f, y2 = pr.y + pr.w * 0.5f;
        float pa = (x2 - x1) * (y2 - y1);
#pragma unroll
        for (int i = 0; i < 4; ++i) {
            float lx = fmaxf(bx[i].x, x1), ly = fmaxf(bx[i].y, y1);
            float hx = fminf(bx[i].z, x2), hy = fminf(bx[i].w, y2);
            float inter = fmaxf(hx - lx, 0.0f) * fmaxf(hy - ly, 0.0f);
            float iou = inter / (a1[i] + pa - inter);  // same expr/order as reference
            if (iou > bv[i]) { bv[i] = iou; bp[i] = p; }  // ascending p: first max
        }
    }
    {   // tail: p = tid + 8704, valid for tid < 28
        int p = tid + 8704;
        if (p < NP) {
            float4 pr = pr4[p];
            float x1 = pr.x - pr.z * 0.5f, y1 = pr.y - pr.w * 0.5f;
            float x2 = pr.x + pr.z * 0.5f, y2 = pr.y + pr.w * 0.5f;
            float pa = (x2 - x1) * (y2 - y1);
#pragma unroll
            for (int i = 0; i < 4; ++i) {
                float lx = fmaxf(bx[i].x, x1), ly = fmaxf(bx[i].y, y1);
                float hx = fminf(bx[i].z, x2), hy = fminf(bx[i].w, y2);
                float inter = fmaxf(hx - lx, 0.0f) * fmaxf(hy - ly, 0.0f);
                float iou = inter / (a1[i] + pa - inter);
                if (iou > bv[i]) { bv[i] = iou; bp[i] = p; }
            }
        }
    }

#pragma unroll
    for (int i = 0; i < 4; ++i) {
        float m = wave64_fmax_u(bv[i]);                      // exact wave max
        int mp = wave64_imin_u((bv[i] == m) ? bp[i] : 0x7FFFFFFF);  // min p @ max
        if (lane == 0)
            part[wid][i] = ((unsigned long long)__float_as_uint(m) << 32) |
                           (unsigned long long)(0xFFFFFFFFu - (unsigned)mp);
    }
    __syncthreads();
    if (tid < 4) {   // combine 4 wave-partials for object o0+tid
        unsigned long long best = part[0][tid];
        if (part[1][tid] > best) best = part[1][tid];
        if (part[2][tid] > best) best = part[2][tid];
        if (part[3][tid] > best) best = part[3][tid];
        pfor[b * NO + o0 + tid] = (int)(0xFFFFFFFFu - (unsigned)(best & 0xFFFFFFFFull));
    }
}

// Best-of-each k_loss: R6 shape (256t, loads AFTER argmax -> VGPR-lean, forced
// list via ballot compaction) + R7's s[lbl] scatter-dword (replaces the
// 20-deep cndmask chain). No ballot div-skip (R9 showed it costs, not saves).
__global__ __launch_bounds__(256) void k_loss(const float* __restrict__ plocs,
                                              const float* __restrict__ scores,
                                              const float* __restrict__ boxes,
                                              const int* __restrict__ labels,
                                              const float* __restrict__ priors,
                                              const int* __restrict__ pfor,
                                              float* __restrict__ confneg,
                                              int* __restrict__ pnp,
                                              double* __restrict__ pd0,
                                              double* __restrict__ pd1,
                                              int* __restrict__ donecnt) {
    __shared__ float4 sbox[NO];
    __shared__ float  sa1[NO];
    __shared__ int    slbl[NO];
    __shared__ int    sfp[NO], sfo[NO];   // compacted forced list (o ascending)
    __shared__ int    snf;
    int b = blockIdx.y;
    int p0 = blockIdx.x * 256;
    int tid = threadIdx.x;

    if (tid < NO) {
        float4 bxx = ((const float4*)boxes)[b * NO + tid];
        sbox[tid] = bxx;
        sa1[tid]  = (bxx.z - bxx.x) * (bxx.w - bxx.y);
        slbl[tid] = labels[b * NO + tid];
    }
    if (tid < 64) {   // wave 0 builds the forced list for this 256-prior window
        int f = -1, inr = 0;
        if (tid < NO) {
            f = pfor[b * NO + tid];
            inr = (f >= p0) && (f < p0 + 256);
        }
        unsigned long long mask = __ballot(inr);
        if (inr) {
            int rank = __popcll(mask & ((1ull << tid) - 1));  // preserves o order
            sfp[rank] = f; sfo[rank] = tid;
        }
        if (tid == 0) snf = __popcll(mask);
    }
    __syncthreads();

    int p = p0 + tid;
    float posconf = 0.0f, locpart = 0.0f;
    int isp = 0;

    if (p < NP) {
        float4 pr = ((const float4*)priors)[p];
        float px1 = pr.x - pr.z * 0.5f, py1 = pr.y - pr.w * 0.5f;
        float px2 = pr.x + pr.z * 0.5f, py2 = pr.y + pr.w * 0.5f;
        float pa  = (px2 - px1) * (py2 - py1);

        // inline per-prior argmax over 32 objects (sbox/sa1 reads are broadcasts);
        // bestv=0 init: all-zero rows -> index 0, matching jnp.argmax
        float bestv = 0.0f; int besto = 0;
#pragma unroll
        for (int o = 0; o < NO; ++o) {
            float4 bxx = sbox[o];
            float lx = fmaxf(bxx.x, px1), ly = fmaxf(bxx.y, py1);
            float hx = fminf(bxx.z, px2), hy = fminf(bxx.w, py2);
            float inter = fmaxf(hx - lx, 0.0f) * fmaxf(hy - ly, 0.0f);
            float iou = inter / (sa1[o] + pa - inter);  // same expr/order as reference
            if (iou > bestv) { bestv = iou; besto = o; }  // first max wins
        }
        int obj = besto;
        int mat = bestv >= 0.5f ? 1 : 0;
        int nf = snf;
        for (int i = 0; i < nf; ++i)              // usually 0-3 entries, o ascending
            if (sfp[i] == p) { obj = sfo[i]; mat = 1; }  // last o wins (scatter)
        int lbl = mat ? slbl[obj] : 0;

        // score row loads (after argmax -> VGPR-lean)
        const float* srow = scores + ((size_t)b * NP + p) * NC;
        const float4* r4 = (const float4*)srow;
        float4 q0 = r4[0], q1 = r4[1], q2 = r4[2], q3 = r4[3], q4 = r4[4];
        float sl = srow[lbl];   // one scatter dword; exact same bits as s[lbl]

        float s[NC] = {q0.x, q0.y, q0.z, q0.w, q1.x, q1.y, q1.z, q1.w,
                       q2.x, q2.y, q2.z, q2.w, q3.x, q3.y, q3.z, q3.w,
                       q4.x, q4.y, q4.z, q4.w, srow[20]};
        float m = s[0];
#pragma unroll
        for (int c = 1; c < NC; ++c) m = fmaxf(m, s[c]);
        float sum = 0.0f;
#pragma unroll
        for (int c = 0; c < NC; ++c) sum += __expf(s[c] - m);  // ascending c order
        float conf = m + __logf(sum) - sl;

        if (lbl != 0) {
            isp = 1;
            posconf = conf;
            float4 bxx = sbox[obj];
            float cx = (bxx.x + bxx.z) * 0.5f, cy = (bxx.y + bxx.w) * 0.5f;
            float w = bxx.z - bxx.x, h = bxx.w - bxx.y;
            float gx = (cx - pr.x) / (pr.z * 0.1f);
            float gy = (cy - pr.y) / (pr.w * 0.1f);
            float gw = __logf(w / pr.z) * 5.0f;
            float gh = __logf(h / pr.w) * 5.0f;
            float4 pl = ((const float4*)plocs)[(size_t)b * NP + p];
            locpart = fabsf(pl.x - gx) + fabsf(pl.y - gy) +
                      fabsf(pl.z - gw) + fabsf(pl.w - gh);
        }
        confneg[(size_t)b * NP + p] = isp ? 0.0f : conf;
    }

    // wave shuffle reduce, then 4-wave LDS combine, one barrier
    for (int s = 32; s > 0; s >>= 1) {
        posconf += __shfl_xor(posconf, s, 64);
        locpart += __shfl_xor(locpart, s, 64);
        isp     += __shfl_xor(isp, s, 64);
    }
    __shared__ float w0[4], w1[4];
    __shared__ int wc[4];
    int wid = tid >> 6, lane = tid & 63;
    if (lane == 0) { w0[wid] = posconf; w1[wid] = locpart; wc[wid] = isp; }
    __syncthreads();
    if (tid == 0) {
        int pb = b * NCHUNK + blockIdx.x;
        pd0[pb] = (double)(w0[0] + w0[1] + w0[2] + w0[3]);
        pd1[pb] = (double)(w1[0] + w1[1] + w1[2] + w1[3]);
        pnp[pb] = wc[0] + wc[1] + wc[2] + wc[3];
        if (pb == 0) *donecnt = 0;   // stream-ordered before k_topk; poison-proof
    }
}

// Exact k-th-largest, radix-4 bit bisection; 16 barrier steps. (R7 version)
__global__ __launch_bounds__(1024) void k_topk(const float* __restrict__ confneg,
                                               const int* __restrict__ pnp,
                                               const double* __restrict__ pd0,
                                               const double* __restrict__ pd1,
                                               int* __restrict__ snp,
                                               double* __restrict__ sums,  // [NB][3] hn,pc,lc
                                               int* __restrict__ donecnt,
                                               float* __restrict__ out) {
    __shared__ unsigned long long sq[2][16];
    __shared__ int    siw[16];
    __shared__ double sdd[16];
    __shared__ int    sk;
    int tid = threadIdx.x, b = blockIdx.x;
    int lane = tid & 63, wid = tid >> 6;

    // prologue: wave 0 reduces the 35 per-chunk partials of image b
    if (wid == 0) {
        int np_ = 0; double d0 = 0.0, d1 = 0.0;
        if (lane < NCHUNK) {
            int pb = b * NCHUNK + lane;
            np_ = pnp[pb]; d0 = pd0[pb]; d1 = pd1[pb];
        }
        for (int s = 32; s > 0; s >>= 1) {
            np_ += __shfl_xor(np_, s, 64);
            d0  += __shfl_xor(d0, s, 64);
            d1  += __shfl_xor(d1, s, 64);
        }
        if (lane == 0) {
            int k = np_ * 3; if (k > NP) k = NP;
            sk = k;
            snp[b] = np_;
            sums[b * 3 + 1] = d0;
            sums[b * 3 + 2] = d1;
        }
    }

    const float* src = confneg + (size_t)b * NP;
    float val[9];
#pragma unroll
    for (int j = 0; j < 9; ++j) {
        int i = tid + j * 1024;
        val[j] = (i < NP) ? src[i] : 0.0f;  // 0 never counts (cand>0)
    }
    __syncthreads();
    int k = sk;

    double hn = 0.0;
    if (k > 0) {   // block-uniform
        unsigned T = 0;
        int par = 0;
        {   // step 1: bit 30 (radix-2)
            unsigned cand = 1u << 30;
            int cnt = 0;
#pragma unroll
            for (int j = 0; j < 9; ++j)
                cnt += __popcll(__ballot(__float_as_uint(val[j]) >= cand));
            if (lane == 0) sq[par][wid] = (unsigned long long)cnt;
            __syncthreads();
            unsigned long long t = 0;
#pragma unroll
            for (int w = 0; w < 16; ++w) t += sq[par][w];
            par ^= 1;
            if ((int)t >= k) T = cand;
        }
        // 15 radix-4 steps over bit pairs (29,28)...(1,0)
        for (int sh = 28; sh >= 0; sh -= 2) {
            unsigned c1 = T | (1u << sh), c2 = T | (2u << sh), c3 = T | (3u << sh);
            int n1 = 0, n2 = 0, n3 = 0;
#pragma unroll
            for (int j = 0; j < 9; ++j) {
                unsigned u = __float_as_uint(val[j]);
                n1 += __popcll(__ballot(u >= c1));
                n2 += __popcll(__ballot(u >= c2));
                n3 += __popcll(__ballot(u >= c3));
            }
            if (lane == 0)
                sq[par][wid] = (unsigned long long)n1 |
                               ((unsigned long long)n2 << 20) |
                               ((unsigned long long)n3 << 40);
            __syncthreads();
            unsigned long long t = 0;
#pragma unroll
            for (int w = 0; w < 16; ++w) t += sq[par][w];
            par ^= 1;
            int t1 = (int)(t & 0xFFFFF), t2 = (int)((t >> 20) & 0xFFFFF),
                t3 = (int)((t >> 40) & 0xFFFFF);
            if      (t3 >= k) T = c3;
            else if (t2 >= k) T = c2;
            else if (t1 >= k) T = c1;   // uniform decision
        }

        int cgt = 0;
        double sgt = 0.0;
#pragma unroll
        for (int j = 0; j < 9; ++j) {
            unsigned u = __float_as_uint(val[j]);
            if (u > T) { cgt++; sgt += (double)val[j]; }
        }
        for (int s = 32; s > 0; s >>= 1) {
            cgt += __shfl_xor(cgt, s, 64);
            sgt += __shfl_xor(sgt, s, 64);
        }
        if (lane == 0) { siw[wid] = cgt; sdd[wid] = sgt; }
        __syncthreads();
        if (tid == 0) {
            int cg = 0; double sg = 0.0;
            for (int w = 0; w < 16; ++w) { cg += siw[w]; sg += sdd[w]; }
            hn = sg + (double)(k - cg) * (double)__uint_as_float(T);
        }
    }
    if (tid == 0) sums[b * 3 + 0] = hn;  // explicit 0 when k<=0 (overwrite poison)

    // ---- last-block final reduction ----
    __shared__ int samlast;
    if (tid == 0) {
        __threadfence();                   // sums/snp stores visible device-wide
        int prev = atomicAdd(donecnt, 1);  // device-scope
        samlast = (prev == NB - 1) ? 1 : 0;
    }
    __syncthreads();
    if (!samlast) return;
    __threadfence();

    double hnn = 0.0, pc = 0.0, lc = 0.0, npd = 0.0;
    if (tid < NB) {   // peer-written: atomic reads to dodge stale caches
        hnn = atomicAdd(&sums[tid * 3 + 0], 0.0);
        pc  = atomicAdd(&sums[tid * 3 + 1], 0.0);
        lc  = atomicAdd(&sums[tid * 3 + 2], 0.0);
        npd = (double)atomicAdd((int*)&snp[tid], 0);
    }
    for (int s = 32; s > 0; s >>= 1) {
        hnn += __shfl_xor(hnn, s, 64);
        pc  += __shfl_xor(pc, s, 64);
        lc  += __shfl_xor(lc, s, 64);
        npd += __shfl_xor(npd, s, 64);
    }
    __shared__ double sfin[4][2];
    if (lane == 0 && wid < 2) {
        sfin[0][wid] = hnn; sfin[1][wid] = pc; sfin[2][wid] = lc; sfin[3][wid] = npd;
    }
    __syncthreads();
    if (tid == 0) {
        double H  = sfin[0][0] + sfin[0][1];
        double P  = sfin[1][0] + sfin[1][1];
        double L  = sfin[2][0] + sfin[2][1];
        double nt = sfin[3][0] + sfin[3][1];
        out[0] = (float)((H + P) / nt + L / (nt * 4.0));
    }
}

extern "C" void kernel_launch(void* const* d_in, const int* in_sizes, int n_in,
                              void* d_out, int out_size, void* d_ws, size_t ws_size,
                              hipStream_t stream) {
    const float* plocs  = (const float*)d_in[0];
    const float* scores = (const float*)d_in[1];
    const float* boxes  = (const float*)d_in[2];
    const int*   labels = (const int*)d_in[3];
    const float* priors = (const float*)d_in[4];
    float* out = (float*)d_out;

    char* ws = (char*)d_ws;
    int*    pfor    = (int*)ws;
    double* pd0     = (double*)(ws + 16384);
    double* pd1     = (double*)(ws + 52224);
    int*    pnp     = (int*)(ws + 88064);
    int*    snp     = (int*)(ws + 105984);
    double* sums    = (double*)(ws + 106496);
    int*    donecnt = (int*)(ws + 109568);
    float*  confneg = (float*)(ws + 109824);

    hipLaunchKernelGGL(k_obj, dim3(NO / 4, NB), dim3(256), 0, stream,
                       boxes, priors, pfor);
    hipLaunchKernelGGL(k_loss, dim3(NCHUNK, NB), dim3(256), 0, stream,
                       plocs, scores, boxes, labels, priors, pfor,
                       confneg, pnp, pd0, pd1, donecnt);
    hipLaunchKernelGGL(k_topk, dim3(NB), dim3(1024), 0, stream,
                       confneg, pnp, pd0, pd1, snp, sums, donecnt, out);
}

// Round 13
// 219.915 us; speedup vs baseline: 1.2644x; 1.0055x over previous
//
#include <hip/hip_runtime.h>

#define NB 128
#define NP 8732
#define NO 32
#define NC 21
#define NCHUNK 35   // k_loss grid.x (256 priors per block)

// ---------------- workspace layout (no zero-init required anywhere) ----------
// pfor   : int[NB*NO]        @ 0        per-(b,o) argmax prior (plain store)
// pd0    : double[NB*35]     @ 16384    per-loss-block pos_conf partial
// pd1    : double[NB*35]     @ 52224    per-loss-block loc partial
// pnp    : int[NB*35]        @ 88064    per-loss-block npos partial
// snp    : int[NB]           @ 105984   per-image npos (k_topk)
// sums   : double[NB*3]      @ 106496   per-image {hn, pos_conf, loc} (k_topk)
// donecnt: int               @ 109568   zeroed by k_loss block pb==0
// confneg: float[NB*NP]      @ 109824

// -------- wave64 reductions via DPP (VALU pipe); result uniform via readlane(63)
__device__ __forceinline__ float wave64_fmax_u(float m) {
    int v;
    v = __builtin_amdgcn_update_dpp(__float_as_int(m), __float_as_int(m), 0x111, 0xf, 0xf, false);
    m = fmaxf(m, __int_as_float(v));
    v = __builtin_amdgcn_update_dpp(__float_as_int(m), __float_as_int(m), 0x112, 0xf, 0xf, false);
    m = fmaxf(m, __int_as_float(v));
    v = __builtin_amdgcn_update_dpp(__float_as_int(m), __float_as_int(m), 0x114, 0xf, 0xf, false);
    m = fmaxf(m, __int_as_float(v));
    v = __builtin_amdgcn_update_dpp(__float_as_int(m), __float_as_int(m), 0x118, 0xf, 0xf, false);
    m = fmaxf(m, __int_as_float(v));
    v = __builtin_amdgcn_update_dpp(__float_as_int(m), __float_as_int(m), 0x142, 0xf, 0xf, false);
    m = fmaxf(m, __int_as_float(v));
    v = __builtin_amdgcn_update_dpp(__float_as_int(m), __float_as_int(m), 0x143, 0xf, 0xf, false);
    m = fmaxf(m, __int_as_float(v));
    return __int_as_float(__builtin_amdgcn_readlane(__float_as_int(m), 63));
}

__device__ __forceinline__ int wave64_imin_u(int m) {
    int v;
    v = __builtin_amdgcn_update_dpp(m, m, 0x111, 0xf, 0xf, false); m = v < m ? v : m;
    v = __builtin_amdgcn_update_dpp(m, m, 0x112, 0xf, 0xf, false); m = v < m ? v : m;
    v = __builtin_amdgcn_update_dpp(m, m, 0x114, 0xf, 0xf, false); m = v < m ? v : m;
    v = __builtin_amdgcn_update_dpp(m, m, 0x118, 0xf, 0xf, false); m = v < m ? v : m;
    v = __builtin_amdgcn_update_dpp(m, m, 0x142, 0xf, 0xf, false); m = v < m ? v : m;
    v = __builtin_amdgcn_update_dpp(m, m, 0x143, 0xf, 0xf, false); m = v < m ? v : m;
    return __builtin_amdgcn_readlane(m, 63);
}

// Per-(b,o) argmax over all priors (R7 version, verified in the 220.36 run).
// grid (8,NB): block owns 4 objects (boxes uniform -> SGPRs); thread scans
// p = tid + 256k (coalesced float4, one load feeds 4 independent argmaxes).
// Per-wave DPP reduce per object, packed u64 partials in LDS, 4-entry combine.
__global__ __launch_bounds__(256) void k_obj(const float* __restrict__ boxes,
                                             const float* __restrict__ priors,
                                             int* __restrict__ pfor) {
    __shared__ unsigned long long part[4][4];   // [wave][object]
    int b = blockIdx.y;
    int tid = threadIdx.x, lane = tid & 63, wid = tid >> 6;
    int o0 = blockIdx.x * 4;

    float4 bx[4]; float a1[4];
#pragma unroll
    for (int i = 0; i < 4; ++i) {
        bx[i] = ((const float4*)boxes)[b * NO + o0 + i];   // uniform -> s_load
        a1[i] = (bx[i].z - bx[i].x) * (bx[i].w - bx[i].y);
    }

    float bv[4] = {-1.0f, -1.0f, -1.0f, -1.0f};
    int   bp[4] = {0, 0, 0, 0};
    const float4* pr4 = (const float4*)priors;

    for (int k = 0; k < 34; ++k) {               // p <= 255+8448 = 8703 < NP
        int p = tid + (k << 8);
        float4 pr = pr4[p];
        float x1 = pr.x - pr.z * 0.5f, y1 = pr.y - pr.w * 0.5f;
        float x2 = pr.x + pr.z * 0.5f, y2 = pr.y + pr.w * 0.5f;
        float pa = (x2 - x1) * (y2 - y1);
#pragma unroll
        for (int i = 0; i < 4; ++i) {
            float lx = fmaxf(bx[i].x, x1), ly = fmaxf(bx[i].y, y1);
            float hx = fminf(bx[i].z, x2), hy = fminf(bx[i].w, y2);
            float inter = fmaxf(hx - lx, 0.0f) * fmaxf(hy - ly, 0.0f);
            float iou = inter / (a1[i] + pa - inter);  // same expr/order as reference
            if (iou > bv[i]) { bv[i] = iou; bp[i] = p; }  // ascending p: first max
        }
    }
    {   // tail: p = tid + 8704, valid for tid < 28
        int p = tid + 8704;
        if (p < NP) {
            float4 pr = pr4[p];
            float x1 = pr.x - pr.z * 0.5f, y1 = pr.y - pr.w * 0.5f;
            float x2 = pr.x + pr.z * 0.5f, y2 = pr.y + pr.w * 0.5f;
            float pa = (x2 - x1) * (y2 - y1);
#pragma unroll
            for (int i = 0; i < 4; ++i) {
                float lx = fmaxf(bx[i].x, x1), ly = fmaxf(bx[i].y, y1);
                float hx = fminf(bx[i].z, x2), hy = fminf(bx[i].w, y2);
                float inter = fmaxf(hx - lx, 0.0f) * fmaxf(hy - ly, 0.0f);
                float iou = inter / (a1[i] + pa - inter);
                if (iou > bv[i]) { bv[i] = iou; bp[i] = p; }
            }
        }
    }

#pragma unroll
    for (int i = 0; i < 4; ++i) {
        float m = wave64_fmax_u(bv[i]);                      // exact wave max
        int mp = wave64_imin_u((bv[i] == m) ? bp[i] : 0x7FFFFFFF);  // min p @ max
        if (lane == 0)
            part[wid][i] = ((unsigned long long)__float_as_uint(m) << 32) |
                           (unsigned long long)(0xFFFFFFFFu - (unsigned)mp);
    }
    __syncthreads();
    if (tid < 4) {   // combine 4 wave-partials for object o0+tid
        unsigned long long best = part[0][tid];
        if (part[1][tid] > best) best = part[1][tid];
        if (part[2][tid] > best) best = part[2][tid];
        if (part[3][tid] > best) best = part[3][tid];
        pfor[b * NO + o0 + tid] = (int)(0xFFFFFFFFu - (unsigned)(best & 0xFFFFFFFFull));
    }
}

// R6 k_loss VERBATIM (the <=53.5us / low-VGPR version): loads after argmax,
// s[lbl] via inline cndmask chain (NO dependent scatter load -> compiler keeps
// the register lifetime short), forced list via ballot compaction.
__global__ __launch_bounds__(256) void k_loss(const float* __restrict__ plocs,
                                              const float* __restrict__ scores,
                                              const float* __restrict__ boxes,
                                              const int* __restrict__ labels,
                                              const float* __restrict__ priors,
                                              const int* __restrict__ pfor,
                                              float* __restrict__ confneg,
                                              int* __restrict__ pnp,
                                              double* __restrict__ pd0,
                                              double* __restrict__ pd1,
                                              int* __restrict__ donecnt) {
    __shared__ float4 sbox[NO];
    __shared__ float  sa1[NO];
    __shared__ int    slbl[NO];
    __shared__ int    sfp[NO], sfo[NO];   // compacted forced list (o ascending)
    __shared__ int    snf;
    int b = blockIdx.y;
    int p0 = blockIdx.x * 256;
    int tid = threadIdx.x;

    if (tid < NO) {
        float4 bxx = ((const float4*)boxes)[b * NO + tid];
        sbox[tid] = bxx;
        sa1[tid]  = (bxx.z - bxx.x) * (bxx.w - bxx.y);
        slbl[tid] = labels[b * NO + tid];
    }
    if (tid < 64) {   // wave 0 builds the forced list for this 256-prior window
        int f = -1, inr = 0;
        if (tid < NO) {
            f = pfor[b * NO + tid];
            inr = (f >= p0) && (f < p0 + 256);
        }
        unsigned long long mask = __ballot(inr);
        if (inr) {
            int rank = __popcll(mask & ((1ull << tid) - 1));  // preserves o order
            sfp[rank] = f; sfo[rank] = tid;
        }
        if (tid == 0) snf = __popcll(mask);
    }
    __syncthreads();

    int p = p0 + tid;
    float posconf = 0.0f, locpart = 0.0f;
    int isp = 0;

    if (p < NP) {
        float4 pr = ((const float4*)priors)[p];
        float px1 = pr.x - pr.z * 0.5f, py1 = pr.y - pr.w * 0.5f;
        float px2 = pr.x + pr.z * 0.5f, py2 = pr.y + pr.w * 0.5f;
        float pa  = (px2 - px1) * (py2 - py1);

        // inline per-prior argmax over 32 objects (sbox/sa1 reads are broadcasts);
        // bestv=0 init: all-zero rows -> index 0, matching jnp.argmax
        float bestv = 0.0f; int besto = 0;
#pragma unroll
        for (int o = 0; o < NO; ++o) {
            float4 bxx = sbox[o];
            float lx = fmaxf(bxx.x, px1), ly = fmaxf(bxx.y, py1);
            float hx = fminf(bxx.z, px2), hy = fminf(bxx.w, py2);
            float inter = fmaxf(hx - lx, 0.0f) * fmaxf(hy - ly, 0.0f);
            float iou = inter / (sa1[o] + pa - inter);  // same expr/order as reference
            if (iou > bestv) { bestv = iou; besto = o; }  // first max wins
        }
        int obj = besto;
        int mat = bestv >= 0.5f ? 1 : 0;
        int nf = snf;
        for (int i = 0; i < nf; ++i)              // usually 0-3 entries, o ascending
            if (sfp[i] == p) { obj = sfo[i]; mat = 1; }  // last o wins (scatter)
        int lbl = mat ? slbl[obj] : 0;

        // direct row load: 5x dwordx4 + 1 dword (dword-aligned; CDNA VMEM
        // multi-dword needs only 4B alignment), all 21 scores in registers
        const float* srow = scores + ((size_t)b * NP + p) * NC;
        const float4* r4 = (const float4*)srow;
        float4 q0 = r4[0], q1 = r4[1], q2 = r4[2], q3 = r4[3], q4 = r4[4];
        float s[NC] = {q0.x, q0.y, q0.z, q0.w, q1.x, q1.y, q1.z, q1.w,
                       q2.x, q2.y, q2.z, q2.w, q3.x, q3.y, q3.z, q3.w,
                       q4.x, q4.y, q4.z, q4.w, srow[20]};
        float m = s[0];
#pragma unroll
        for (int c = 1; c < NC; ++c) m = fmaxf(m, s[c]);
        float sum = 0.0f, sl = s[0];
#pragma unroll
        for (int c = 0; c < NC; ++c) {
            sum += __expf(s[c] - m);               // ascending c: same order as before
            if (c > 0) sl = (lbl == c) ? s[c] : sl;  // static-index extract of s[lbl]
        }
        float conf = m + __logf(sum) - sl;

        if (lbl != 0) {
            isp = 1;
            posconf = conf;
            float4 bxx = sbox[obj];
            float cx = (bxx.x + bxx.z) * 0.5f, cy = (bxx.y + bxx.w) * 0.5f;
            float w = bxx.z - bxx.x, h = bxx.w - bxx.y;
            float gx = (cx - pr.x) / (pr.z * 0.1f);
            float gy = (cy - pr.y) / (pr.w * 0.1f);
            float gw = __logf(w / pr.z) * 5.0f;
            float gh = __logf(h / pr.w) * 5.0f;
            float4 pl = ((const float4*)plocs)[(size_t)b * NP + p];
            locpart = fabsf(pl.x - gx) + fabsf(pl.y - gy) +
                      fabsf(pl.z - gw) + fabsf(pl.w - gh);
        }
        confneg[(size_t)b * NP + p] = isp ? 0.0f : conf;
    }

    // wave shuffle reduce, then 4-wave LDS combine, one barrier
    for (int s = 32; s > 0; s >>= 1) {
        posconf += __shfl_xor(posconf, s, 64);
        locpart += __shfl_xor(locpart, s, 64);
        isp     += __shfl_xor(isp, s, 64);
    }
    __shared__ float w0[4], w1[4];
    __shared__ int wc[4];
    int wid = tid >> 6, lane = tid & 63;
    if (lane == 0) { w0[wid] = posconf; w1[wid] = locpart; wc[wid] = isp; }
    __syncthreads();
    if (tid == 0) {
        int pb = b * NCHUNK + blockIdx.x;
        pd0[pb] = (double)(w0[0] + w0[1] + w0[2] + w0[3]);
        pd1[pb] = (double)(w1[0] + w1[1] + w1[2] + w1[3]);
        pnp[pb] = wc[0] + wc[1] + wc[2] + wc[3];
        if (pb == 0) *donecnt = 0;   // stream-ordered before k_topk; poison-proof
    }
}

// Exact k-th-largest, radix-4 bit bisection; 16 barrier steps. (R7 version)
__global__ __launch_bounds__(1024) void k_topk(const float* __restrict__ confneg,
                                               const int* __restrict__ pnp,
                                               const double* __restrict__ pd0,
                                               const double* __restrict__ pd1,
                                               int* __restrict__ snp,
                                               double* __restrict__ sums,  // [NB][3] hn,pc,lc
                                               int* __restrict__ donecnt,
                                               float* __restrict__ out) {
    __shared__ unsigned long long sq[2][16];
    __shared__ int    siw[16];
    __shared__ double sdd[16];
    __shared__ int    sk;
    int tid = threadIdx.x, b = blockIdx.x;
    int lane = tid & 63, wid = tid >> 6;

    // prologue: wave 0 reduces the 35 per-chunk partials of image b
    if (wid == 0) {
        int np_ = 0; double d0 = 0.0, d1 = 0.0;
        if (lane < NCHUNK) {
            int pb = b * NCHUNK + lane;
            np_ = pnp[pb]; d0 = pd0[pb]; d1 = pd1[pb];
        }
        for (int s = 32; s > 0; s >>= 1) {
            np_ += __shfl_xor(np_, s, 64);
            d0  += __shfl_xor(d0, s, 64);
            d1  += __shfl_xor(d1, s, 64);
        }
        if (lane == 0) {
            int k = np_ * 3; if (k > NP) k = NP;
            sk = k;
            snp[b] = np_;
            sums[b * 3 + 1] = d0;
            sums[b * 3 + 2] = d1;
        }
    }

    const float* src = confneg + (size_t)b * NP;
    float val[9];
#pragma unroll
    for (int j = 0; j < 9; ++j) {
        int i = tid + j * 1024;
        val[j] = (i < NP) ? src[i] : 0.0f;  // 0 never counts (cand>0)
    }
    __syncthreads();
    int k = sk;

    double hn = 0.0;
    if (k > 0) {   // block-uniform
        unsigned T = 0;
        int par = 0;
        {   // step 1: bit 30 (radix-2)
            unsigned cand = 1u << 30;
            int cnt = 0;
#pragma unroll
            for (int j = 0; j < 9; ++j)
                cnt += __popcll(__ballot(__float_as_uint(val[j]) >= cand));
            if (lane == 0) sq[par][wid] = (unsigned long long)cnt;
            __syncthreads();
            unsigned long long t = 0;
#pragma unroll
            for (int w = 0; w < 16; ++w) t += sq[par][w];
            par ^= 1;
            if ((int)t >= k) T = cand;
        }
        // 15 radix-4 steps over bit pairs (29,28)...(1,0)
        for (int sh = 28; sh >= 0; sh -= 2) {
            unsigned c1 = T | (1u << sh), c2 = T | (2u << sh), c3 = T | (3u << sh);
            int n1 = 0, n2 = 0, n3 = 0;
#pragma unroll
            for (int j = 0; j < 9; ++j) {
                unsigned u = __float_as_uint(val[j]);
                n1 += __popcll(__ballot(u >= c1));
                n2 += __popcll(__ballot(u >= c2));
                n3 += __popcll(__ballot(u >= c3));
            }
            if (lane == 0)
                sq[par][wid] = (unsigned long long)n1 |
                               ((unsigned long long)n2 << 20) |
                               ((unsigned long long)n3 << 40);
            __syncthreads();
            unsigned long long t = 0;
#pragma unroll
            for (int w = 0; w < 16; ++w) t += sq[par][w];
            par ^= 1;
            int t1 = (int)(t & 0xFFFFF), t2 = (int)((t >> 20) & 0xFFFFF),
                t3 = (int)((t >> 40) & 0xFFFFF);
            if      (t3 >= k) T = c3;
            else if (t2 >= k) T = c2;
            else if (t1 >= k) T = c1;   // uniform decision
        }

        int cgt = 0;
        double sgt = 0.0;
#pragma unroll
        for (int j = 0; j < 9; ++j) {
            unsigned u = __float_as_uint(val[j]);
            if (u > T) { cgt++; sgt += (double)val[j]; }
        }
        for (int s = 32; s > 0; s >>= 1) {
            cgt += __shfl_xor(cgt, s, 64);
            sgt += __shfl_xor(sgt, s, 64);
        }
        if (lane == 0) { siw[wid] = cgt; sdd[wid] = sgt; }
        __syncthreads();
        if (tid == 0) {
            int cg = 0; double sg = 0.0;
            for (int w = 0; w < 16; ++w) { cg += siw[w]; sg += sdd[w]; }
            hn = sg + (double)(k - cg) * (double)__uint_as_float(T);
        }
    }
    if (tid == 0) sums[b * 3 + 0] = hn;  // explicit 0 when k<=0 (overwrite poison)

    // ---- last-block final reduction ----
    __shared__ int samlast;
    if (tid == 0) {
        __threadfence();                   // sums/snp stores visible device-wide
        int prev = atomicAdd(donecnt, 1);  // device-scope
        samlast = (prev == NB - 1) ? 1 : 0;
    }
    __syncthreads();
    if (!samlast) return;
    __threadfence();

    double hnn = 0.0, pc = 0.0, lc = 0.0, npd = 0.0;
    if (tid < NB) {   // peer-written: atomic reads to dodge stale caches
        hnn = atomicAdd(&sums[tid * 3 + 0], 0.0);
        pc  = atomicAdd(&sums[tid * 3 + 1], 0.0);
        lc  = atomicAdd(&sums[tid * 3 + 2], 0.0);
        npd = (double)atomicAdd((int*)&snp[tid], 0);
    }
    for (int s = 32; s > 0; s >>= 1) {
        hnn += __shfl_xor(hnn, s, 64);
        pc  += __shfl_xor(pc, s, 64);
        lc  += __shfl_xor(lc, s, 64);
        npd += __shfl_xor(npd, s, 64);
    }
    __shared__ double sfin[4][2];
    if (lane == 0 && wid < 2) {
        sfin[0][wid] = hnn; sfin[1][wid] = pc; sfin[2][wid] = lc; sfin[3][wid] = npd;
    }
    __syncthreads();
    if (tid == 0) {
        double H  = sfin[0][0] + sfin[0][1];
        double P  = sfin[1][0] + sfin[1][1];
        double L  = sfin[2][0] + sfin[2][1];
        double nt = sfin[3][0] + sfin[3][1];
        out[0] = (float)((H + P) / nt + L / (nt * 4.0));
    }
}

extern "C" void kernel_launch(void* const* d_in, const int* in_sizes, int n_in,
                              void* d_out, int out_size, void* d_ws, size_t ws_size,
                              hipStream_t stream) {
    const float* plocs  = (const float*)d_in[0];
    const float* scores = (const float*)d_in[1];
    const float* boxes  = (const float*)d_in[2];
    const int*   labels = (const int*)d_in[3];
    const float* priors = (const float*)d_in[4];
    float* out = (float*)d_out;

    char* ws = (char*)d_ws;
    int*    pfor    = (int*)ws;
    double* pd0     = (double*)(ws + 16384);
    double* pd1     = (double*)(ws + 52224);
    int*    pnp     = (int*)(ws + 88064);
    int*    snp     = (int*)(ws + 105984);
    double* sums    = (double*)(ws + 106496);
    int*    donecnt = (int*)(ws + 109568);
    float*  confneg = (float*)(ws + 109824);

    hipLaunchKernelGGL(k_obj, dim3(NO / 4, NB), dim3(256), 0, stream,
                       boxes, priors, pfor);
    hipLaunchKernelGGL(k_loss, dim3(NCHUNK, NB), dim3(256), 0, stream,
                       plocs, scores, boxes, labels, priors, pfor,
                       confneg, pnp, pd0, pd1, donecnt);
    hipLaunchKernelGGL(k_topk, dim3(NB), dim3(1024), 0, stream,
                       confneg, pnp, pd0, pd1, snp, sums, donecnt, out);
}